// Round 2
// baseline (9486.720 us; speedup 1.0000x reference)
//
#include <hip/hip_runtime.h>

#define B_IMG 512
#define C1OFF (-1.2432432432432432f)

__device__ __forceinline__ float relu_(float v) { return v > 0.f ? v : 0.f; }

__device__ __forceinline__ void loadrow12(const float* __restrict__ p, float r[12]) {
    float4 a = *(const float4*)(p);
    float4 b = *(const float4*)(p + 4);
    float4 c = *(const float4*)(p + 8);
    r[0]=a.x; r[1]=a.y; r[2]=a.z;  r[3]=a.w;
    r[4]=b.x; r[5]=b.y; r[6]=b.z;  r[7]=b.w;
    r[8]=c.x; r[9]=c.y; r[10]=c.z; r[11]=c.w;
}

// ---------------- FC: h = relu(x @ W^T + b), M=512 K=3600 N=3600 -------------
__global__ __launch_bounds__(256) void fc_kernel(
    const float* __restrict__ X, const float* __restrict__ W,
    const float* __restrict__ Bv, float* __restrict__ H)
{
    __shared__ __align__(16) float As[16][68];
    __shared__ __align__(16) float Bs[16][68];
    const int tid = threadIdx.x;
    const int m0 = blockIdx.y * 64;
    const int n0 = blockIdx.x * 64;
    const int tm = tid >> 4, tn = tid & 15;
    const int lr = tid >> 2;            // 0..63
    const int lk = (tid & 3) << 2;      // 0,4,8,12
    const bool bvalid = (n0 + lr) < 3600;
    const float* Arow = X + (size_t)(m0 + lr) * 3600 + lk;
    const float* Brow = W + (size_t)(bvalid ? (n0 + lr) : 0) * 3600 + lk;
    float acc[4][4] = {};
    for (int k0 = 0; k0 < 3600; k0 += 16) {
        float4 av = *(const float4*)(Arow + k0);
        float4 bv = make_float4(0.f, 0.f, 0.f, 0.f);
        if (bvalid) bv = *(const float4*)(Brow + k0);
        __syncthreads();
        As[lk + 0][lr] = av.x; As[lk + 1][lr] = av.y;
        As[lk + 2][lr] = av.z; As[lk + 3][lr] = av.w;
        Bs[lk + 0][lr] = bv.x; Bs[lk + 1][lr] = bv.y;
        Bs[lk + 2][lr] = bv.z; Bs[lk + 3][lr] = bv.w;
        __syncthreads();
        #pragma unroll
        for (int kk = 0; kk < 16; ++kk) {
            float a[4], b[4];
            *(float4*)a = *(const float4*)&As[kk][tm << 2];
            *(float4*)b = *(const float4*)&Bs[kk][tn << 2];
            #pragma unroll
            for (int i = 0; i < 4; ++i)
                #pragma unroll
                for (int j = 0; j < 4; ++j)
                    acc[i][j] = fmaf(a[i], b[j], acc[i][j]);
        }
    }
    #pragma unroll
    for (int i = 0; i < 4; ++i) {
        int m = m0 + (tm << 2) + i;
        #pragma unroll
        for (int j = 0; j < 4; ++j) {
            int n = n0 + (tn << 2) + j;
            if (n < 3600) {
                float v = acc[i][j] + Bv[n];
                H[(size_t)m * 3600 + n] = relu_(v);
            }
        }
    }
}

// ---------------- padding formula (build_padded fused) -----------------------
__device__ __forceinline__ float pad_core(const float* __restrict__ xb,
                                          const float* __restrict__ hb,
                                          int ch, int r, int c)
{
    if (r < 16) return 0.f;                 // top zero (cols >= 16 path)
    int rr = (r <= 75) ? r : (151 - r);     // bottom mirror
    int cc = (c <= 75) ? c : (151 - c);     // right mirror
    int i = rr - 16, j = cc - 16;
    if (ch == 0) return xb[i * 60 + j];
    if (ch == 1) return hb[i * 60 + j];
    return (j >= 51) ? 1.0f : ((j >= 41) ? 0.5f : 0.0f);   // ff channel
}

__device__ __forceinline__ float pad_val(const float* __restrict__ xb,
                                         const float* __restrict__ hb,
                                         int ch, int r, int c)
{
    if (c >= 16) return pad_core(xb, hb, ch, r, c);
    float v = pad_core(xb, hb, ch, r, 31 - c);   // left mirror across col 16
    return (ch == 1) ? (C1OFF - v) : v;
}

// materialize padded canvas (B,3,92,92) into workspace
__global__ __launch_bounds__(256) void pad_kernel(
    const float* __restrict__ x, const float* __restrict__ h,
    float* __restrict__ pad)
{
    const int b = blockIdx.x;
    const float* xb = x + (size_t)b * 3600;
    const float* hb = h + (size_t)b * 3600;
    float* pb = pad + (size_t)b * (3 * 92 * 92);
    for (int i = threadIdx.x; i < 3 * 92 * 92; i += 256) {
        int ch = i / 8464;
        int rem = i - ch * 8464;
        int r = rem / 92;
        int c = rem - r * 92;
        pb[i] = pad_val(xb, hb, ch, r, c);
    }
}

// ---- convA: generic valid 9x9, OC=8 folded into registers, zero LDS ---------
// step KY: output rows (oy,oy+1) use input rows (oy+KY, oy+KY+1) = (TOP, BOT)
#define ASTEP(TOP, BOT, KY)                                                \
    do {                                                                   \
        loadrow12(rp + ((KY) + 1) * IW, (BOT));                            \
        _Pragma("unroll")                                                  \
        for (int oc = 0; oc < 8; ++oc) {                                   \
            const float* wr = wb + oc * (IC * 81) + (KY) * 9;              \
            _Pragma("unroll")                                              \
            for (int kx = 0; kx < 9; ++kx) {                               \
                float w = wr[kx];                                          \
                _Pragma("unroll")                                          \
                for (int j = 0; j < 4; ++j) {                              \
                    acc[oc][0][j] = fmaf(w, (TOP)[kx + j], acc[oc][0][j]); \
                    acc[oc][1][j] = fmaf(w, (BOT)[kx + j], acc[oc][1][j]); \
                }                                                          \
            }                                                              \
        }                                                                  \
    } while (0)

template<int IC, int IH, bool RELU>
__global__ __launch_bounds__(256, 4) void convA(
    const float* __restrict__ in, const float* __restrict__ wt,
    const float* __restrict__ bias, float* __restrict__ out)
{
    constexpr int IW = IH, OH = IH - 8, OW = OH;
    constexpr int NGX = OW / 4, NGY = OH / 2, NP = NGX * NGY;
    const int b = blockIdx.y;
    int p = blockIdx.x * 256 + threadIdx.x;
    const bool act = (p < NP);
    if (!act) p = NP - 1;
    const int gy = p / NGX;
    const int gx = p - gy * NGX;
    const int oy = gy * 2, x0 = gx * 4;
    const float* ib = in + (size_t)b * IC * IH * IW + (size_t)oy * IW + x0;

    float acc[8][2][4];
    #pragma unroll
    for (int oc = 0; oc < 8; ++oc) {
        float bv = bias[oc];
        #pragma unroll
        for (int r = 0; r < 2; ++r)
            #pragma unroll
            for (int j = 0; j < 4; ++j) acc[oc][r][j] = bv;
    }

    #pragma unroll 1
    for (int ic = 0; ic < IC; ++ic) {
        const float* rp = ib + (size_t)ic * IH * IW;
        const float* wb = wt + ic * 81;
        float rA[12], rB[12];
        loadrow12(rp, rA);
        #pragma unroll 1
        for (int t = 0; t < 4; ++t) {
            ASTEP(rA, rB, 2 * t);
            ASTEP(rB, rA, 2 * t + 1);
        }
        ASTEP(rA, rB, 8);
    }

    if (act) {
        #pragma unroll
        for (int oc = 0; oc < 8; ++oc) {
            float* ob = out + ((size_t)b * 8 + oc) * (OH * OW)
                        + (size_t)oy * OW + x0;
            #pragma unroll
            for (int r = 0; r < 2; ++r) {
                float4 v;
                if (RELU) {
                    v = make_float4(relu_(acc[oc][r][0]), relu_(acc[oc][r][1]),
                                    relu_(acc[oc][r][2]), relu_(acc[oc][r][3]));
                } else {
                    v = make_float4(acc[oc][r][0], acc[oc][r][1],
                                    acc[oc][r][2], acc[oc][r][3]);
                }
                *(float4*)&ob[(size_t)r * OW] = v;
            }
        }
    }
}

// ---- convB: conv4 (8->1), 4x4 patch, 4-row rolling window, zero LDS ---------
#define BSTEP(K, QA, QB, QC, QD)                                   \
    do {                                                           \
        loadrow12(rp + ((K) + 3) * IW, (QD));                      \
        const float* wr = wb + (K) * 9;                            \
        _Pragma("unroll")                                          \
        for (int kx = 0; kx < 9; ++kx) {                           \
            float w = wr[kx];                                      \
            _Pragma("unroll")                                      \
            for (int j = 0; j < 4; ++j) {                          \
                acc[0][j] = fmaf(w, (QA)[kx + j], acc[0][j]);      \
                acc[1][j] = fmaf(w, (QB)[kx + j], acc[1][j]);      \
                acc[2][j] = fmaf(w, (QC)[kx + j], acc[2][j]);      \
                acc[3][j] = fmaf(w, (QD)[kx + j], acc[3][j]);      \
            }                                                      \
        }                                                          \
    } while (0)

__global__ __launch_bounds__(256, 4) void convB(
    const float* __restrict__ in, const float* __restrict__ wt,
    const float* __restrict__ bias, float* __restrict__ out)
{
    constexpr int IH = 68, IW = 68, OW = 60;
    constexpr int NGX = 15, NP = 225;
    const int b = blockIdx.x;
    int p = threadIdx.x;
    const bool act = (p < NP);
    if (!act) p = NP - 1;
    const int gy = p / NGX;
    const int gx = p - gy * NGX;
    const int oy = gy * 4, x0 = gx * 4;
    const float* ib = in + (size_t)b * 8 * IH * IW + (size_t)oy * IW + x0;

    float bv = bias[0];
    float acc[4][4];
    #pragma unroll
    for (int r = 0; r < 4; ++r)
        #pragma unroll
        for (int j = 0; j < 4; ++j) acc[r][j] = bv;

    #pragma unroll 1
    for (int ic = 0; ic < 8; ++ic) {
        const float* rp = ib + (size_t)ic * IH * IW;
        const float* wb = wt + ic * 81;
        float q0[12], q1[12], q2[12], q3[12];
        loadrow12(rp + 0 * IW, q0);
        loadrow12(rp + 1 * IW, q1);
        loadrow12(rp + 2 * IW, q2);
        BSTEP(0, q0, q1, q2, q3);
        BSTEP(1, q1, q2, q3, q0);
        BSTEP(2, q2, q3, q0, q1);
        BSTEP(3, q3, q0, q1, q2);
        BSTEP(4, q0, q1, q2, q3);
        BSTEP(5, q1, q2, q3, q0);
        BSTEP(6, q2, q3, q0, q1);
        BSTEP(7, q3, q0, q1, q2);
        BSTEP(8, q0, q1, q2, q3);
    }

    if (act) {
        float* ob = out + (size_t)b * 3600 + (size_t)oy * OW + x0;
        #pragma unroll
        for (int r = 0; r < 4; ++r)
            *(float4*)&ob[(size_t)r * OW] =
                make_float4(acc[r][0], acc[r][1], acc[r][2], acc[r][3]);
    }
}

extern "C" void kernel_launch(void* const* d_in, const int* in_sizes, int n_in,
                              void* d_out, int out_size, void* d_ws, size_t ws_size,
                              hipStream_t stream)
{
    const float* x   = (const float*)d_in[0];
    const float* fcw = (const float*)d_in[1];
    const float* fcb = (const float*)d_in[2];
    const float* w1  = (const float*)d_in[3];
    const float* b1  = (const float*)d_in[4];
    const float* w2  = (const float*)d_in[5];
    const float* b2  = (const float*)d_in[6];
    const float* w3  = (const float*)d_in[7];
    const float* b3  = (const float*)d_in[8];
    const float* w4  = (const float*)d_in[9];
    const float* b4  = (const float*)d_in[10];

    float* h = (float*)d_out;   // h lives in d_out (512*3600)

    // workspace: pad(3*92*92) | t1(8*84*84, also conv3 out) | t2(8*76*76)
    const size_t PADN = 3 * 92 * 92;   // 25392
    const size_t T1N  = 8 * 84 * 84;   // 56448
    const size_t T2N  = 8 * 76 * 76;   // 46208
    size_t per_img = (PADN + T1N + T2N) * sizeof(float);
    int CH = (int)(ws_size / per_img);
    if (CH > B_IMG) CH = B_IMG;
    if (CH < 1) CH = 1;
    float* pad = (float*)d_ws;
    float* t1  = pad + (size_t)CH * PADN;
    float* t2  = t1 + (size_t)CH * T1N;

    fc_kernel<<<dim3(57, 8), 256, 0, stream>>>(x, fcw, fcb, h);

    for (int it = 0; it < 5; ++it) {
        for (int c0 = 0; c0 < B_IMG; c0 += CH) {
            int cn = (B_IMG - c0) < CH ? (B_IMG - c0) : CH;
            pad_kernel<<<cn, 256, 0, stream>>>(x + (size_t)c0 * 3600,
                                               h + (size_t)c0 * 3600, pad);
            convA<3, 92, true><<<dim3(4, cn), 256, 0, stream>>>(pad, w1, b1, t1);
            convA<8, 84, true><<<dim3(3, cn), 256, 0, stream>>>(t1, w2, b2, t2);
            convA<8, 76, true><<<dim3(3, cn), 256, 0, stream>>>(t2, w3, b3, t1);
            convB<<<cn, 256, 0, stream>>>(t1, w4, b4, h + (size_t)c0 * 3600);
        }
    }
}

// Round 3
// 4125.148 us; speedup vs baseline: 2.2997x; 2.2997x over previous
//
#include <hip/hip_runtime.h>

#define B_IMG 512
#define C1OFF (-1.2432432432432432f)

__device__ __forceinline__ float relu_(float v) { return v > 0.f ? v : 0.f; }

__device__ __forceinline__ void loadrow12(const float* __restrict__ p, float r[12]) {
    float4 a = *(const float4*)(p);
    float4 b = *(const float4*)(p + 4);
    float4 c = *(const float4*)(p + 8);
    r[0]=a.x; r[1]=a.y; r[2]=a.z;  r[3]=a.w;
    r[4]=b.x; r[5]=b.y; r[6]=b.z;  r[7]=b.w;
    r[8]=c.x; r[9]=c.y; r[10]=c.z; r[11]=c.w;
}

// ---------------- FC: h = relu(x @ W^T + b), M=512 K=3600 N=3600 -------------
__global__ __launch_bounds__(256) void fc_kernel(
    const float* __restrict__ X, const float* __restrict__ W,
    const float* __restrict__ Bv, float* __restrict__ H)
{
    __shared__ __align__(16) float As[16][68];
    __shared__ __align__(16) float Bs[16][68];
    const int tid = threadIdx.x;
    const int m0 = blockIdx.y * 64;
    const int n0 = blockIdx.x * 64;
    const int tm = tid >> 4, tn = tid & 15;
    const int lr = tid >> 2;            // 0..63
    const int lk = (tid & 3) << 2;      // 0,4,8,12
    const bool bvalid = (n0 + lr) < 3600;
    const float* Arow = X + (size_t)(m0 + lr) * 3600 + lk;
    const float* Brow = W + (size_t)(bvalid ? (n0 + lr) : 0) * 3600 + lk;
    float acc[4][4] = {};
    for (int k0 = 0; k0 < 3600; k0 += 16) {
        float4 av = *(const float4*)(Arow + k0);
        float4 bv = make_float4(0.f, 0.f, 0.f, 0.f);
        if (bvalid) bv = *(const float4*)(Brow + k0);
        __syncthreads();
        As[lk + 0][lr] = av.x; As[lk + 1][lr] = av.y;
        As[lk + 2][lr] = av.z; As[lk + 3][lr] = av.w;
        Bs[lk + 0][lr] = bv.x; Bs[lk + 1][lr] = bv.y;
        Bs[lk + 2][lr] = bv.z; Bs[lk + 3][lr] = bv.w;
        __syncthreads();
        #pragma unroll
        for (int kk = 0; kk < 16; ++kk) {
            float a[4], b[4];
            *(float4*)a = *(const float4*)&As[kk][tm << 2];
            *(float4*)b = *(const float4*)&Bs[kk][tn << 2];
            #pragma unroll
            for (int i = 0; i < 4; ++i)
                #pragma unroll
                for (int j = 0; j < 4; ++j)
                    acc[i][j] = fmaf(a[i], b[j], acc[i][j]);
        }
    }
    #pragma unroll
    for (int i = 0; i < 4; ++i) {
        int m = m0 + (tm << 2) + i;
        #pragma unroll
        for (int j = 0; j < 4; ++j) {
            int n = n0 + (tn << 2) + j;
            if (n < 3600) {
                float v = acc[i][j] + Bv[n];
                H[(size_t)m * 3600 + n] = relu_(v);
            }
        }
    }
}

// ---------------- padding formula (build_padded fused) -----------------------
__device__ __forceinline__ float pad_core(const float* __restrict__ xb,
                                          const float* __restrict__ hb,
                                          int ch, int r, int c)
{
    if (r < 16) return 0.f;                 // top zero (cols >= 16 path)
    int rr = (r <= 75) ? r : (151 - r);     // bottom mirror
    int cc = (c <= 75) ? c : (151 - c);     // right mirror
    int i = rr - 16, j = cc - 16;
    if (ch == 0) return xb[i * 60 + j];
    if (ch == 1) return hb[i * 60 + j];
    return (j >= 51) ? 1.0f : ((j >= 41) ? 0.5f : 0.0f);   // ff channel
}

__device__ __forceinline__ float pad_val(const float* __restrict__ xb,
                                         const float* __restrict__ hb,
                                         int ch, int r, int c)
{
    if (c >= 16) return pad_core(xb, hb, ch, r, c);
    float v = pad_core(xb, hb, ch, r, 31 - c);   // left mirror across col 16
    return (ch == 1) ? (C1OFF - v) : v;
}

// materialize padded canvas (B,3,92,92) into workspace
__global__ __launch_bounds__(256) void pad_kernel(
    const float* __restrict__ x, const float* __restrict__ h,
    float* __restrict__ pad)
{
    const int b = blockIdx.x;
    const float* xb = x + (size_t)b * 3600;
    const float* hb = h + (size_t)b * 3600;
    float* pb = pad + (size_t)b * (3 * 92 * 92);
    for (int i = threadIdx.x; i < 3 * 92 * 92; i += 256) {
        int ch = i / 8464;
        int rem = i - ch * 8464;
        int r = rem / 92;
        int c = rem - r * 92;
        pb[i] = pad_val(xb, hb, ch, r, c);
    }
}

// ---- convA: valid 9x9, 8 oc in registers, 1 output row x 4 cols, no LDS -----
// live set: acc[8][4]=32 + r[12] + addressing ~= 50-70 VGPR -> no spills
template<int IC, int IH, bool RELU>
__global__ __launch_bounds__(256, 4) void convA(
    const float* __restrict__ in, const float* __restrict__ wt,
    const float* __restrict__ bias, float* __restrict__ out)
{
    constexpr int IW = IH, OH = IH - 8, OW = OH;
    constexpr int NGX = OW / 4, NP = OH * NGX;
    const int b = blockIdx.y;
    int p = blockIdx.x * 256 + threadIdx.x;
    const bool act = (p < NP);
    if (!act) p = NP - 1;
    const int oy = p / NGX;
    const int x0 = (p - oy * NGX) * 4;
    const float* ib = in + (size_t)b * IC * IH * IW + (size_t)oy * IW + x0;

    float acc[8][4];
    #pragma unroll
    for (int oc = 0; oc < 8; ++oc) {
        float bv = bias[oc];
        #pragma unroll
        for (int j = 0; j < 4; ++j) acc[oc][j] = bv;
    }

    #pragma unroll 1
    for (int ic = 0; ic < IC; ++ic) {
        const float* rp = ib + (size_t)ic * IH * IW;
        const float* wb = wt + ic * 81;   // + oc*IC*81 + ky*9 + kx (all imm)
        #pragma unroll
        for (int ky = 0; ky < 9; ++ky) {
            float r[12];
            loadrow12(rp + ky * IW, r);
            #pragma unroll
            for (int oc = 0; oc < 8; ++oc) {
                #pragma unroll
                for (int kx = 0; kx < 9; ++kx) {
                    float w = wb[oc * (IC * 81) + ky * 9 + kx];
                    #pragma unroll
                    for (int j = 0; j < 4; ++j)
                        acc[oc][j] = fmaf(w, r[kx + j], acc[oc][j]);
                }
            }
        }
    }

    if (act) {
        #pragma unroll
        for (int oc = 0; oc < 8; ++oc) {
            float* ob = out + ((size_t)b * 8 + oc) * (OH * OW)
                        + (size_t)oy * OW + x0;
            float4 v;
            if (RELU) {
                v = make_float4(relu_(acc[oc][0]), relu_(acc[oc][1]),
                                relu_(acc[oc][2]), relu_(acc[oc][3]));
            } else {
                v = make_float4(acc[oc][0], acc[oc][1], acc[oc][2], acc[oc][3]);
            }
            *(float4*)&ob[0] = v;
        }
    }
}

// ---- convB: conv4 (8->1), 2 output rows, rolling row pair, no LDS -----------
#define BSTEP(TOP, BOT, KY)                                        \
    do {                                                           \
        loadrow12(rp + ((KY) + 1) * IW, (BOT));                    \
        _Pragma("unroll")                                          \
        for (int kx = 0; kx < 9; ++kx) {                           \
            float w = wb[(KY) * 9 + kx];                           \
            _Pragma("unroll")                                      \
            for (int j = 0; j < 4; ++j) {                          \
                acc0[j] = fmaf(w, (TOP)[kx + j], acc0[j]);         \
                acc1[j] = fmaf(w, (BOT)[kx + j], acc1[j]);         \
            }                                                      \
        }                                                          \
    } while (0)

__global__ __launch_bounds__(256, 4) void convB(
    const float* __restrict__ in, const float* __restrict__ wt,
    const float* __restrict__ bias, float* __restrict__ out)
{
    constexpr int IH = 68, IW = 68, OW = 60;
    constexpr int NGX = 15, NP = 450;          // 30 row-pairs x 15 col-groups
    const int b = blockIdx.y;
    int p = blockIdx.x * 256 + threadIdx.x;
    const bool act = (p < NP);
    if (!act) p = NP - 1;
    const int gy = p / NGX;
    const int gx = p - gy * NGX;
    const int oy = gy * 2, x0 = gx * 4;
    const float* ib = in + (size_t)b * 8 * IH * IW + (size_t)oy * IW + x0;

    float bv = bias[0];
    float acc0[4] = {bv, bv, bv, bv}, acc1[4] = {bv, bv, bv, bv};

    #pragma unroll 1
    for (int ic = 0; ic < 8; ++ic) {
        const float* rp = ib + (size_t)ic * IH * IW;
        const float* wb = wt + ic * 81;
        float rA[12], rB[12];
        loadrow12(rp, rA);
        BSTEP(rA, rB, 0); BSTEP(rB, rA, 1); BSTEP(rA, rB, 2);
        BSTEP(rB, rA, 3); BSTEP(rA, rB, 4); BSTEP(rB, rA, 5);
        BSTEP(rA, rB, 6); BSTEP(rB, rA, 7); BSTEP(rA, rB, 8);
    }

    if (act) {
        float* ob = out + (size_t)b * 3600 + (size_t)oy * OW + x0;
        *(float4*)&ob[0]  = make_float4(acc0[0], acc0[1], acc0[2], acc0[3]);
        *(float4*)&ob[OW] = make_float4(acc1[0], acc1[1], acc1[2], acc1[3]);
    }
}

extern "C" void kernel_launch(void* const* d_in, const int* in_sizes, int n_in,
                              void* d_out, int out_size, void* d_ws, size_t ws_size,
                              hipStream_t stream)
{
    const float* x   = (const float*)d_in[0];
    const float* fcw = (const float*)d_in[1];
    const float* fcb = (const float*)d_in[2];
    const float* w1  = (const float*)d_in[3];
    const float* b1  = (const float*)d_in[4];
    const float* w2  = (const float*)d_in[5];
    const float* b2  = (const float*)d_in[6];
    const float* w3  = (const float*)d_in[7];
    const float* b3  = (const float*)d_in[8];
    const float* w4  = (const float*)d_in[9];
    const float* b4  = (const float*)d_in[10];

    float* h = (float*)d_out;   // h lives in d_out (512*3600)

    // workspace: pad(3*92*92) | t1(8*84*84, also conv3 out) | t2(8*76*76)
    const size_t PADN = 3 * 92 * 92;   // 25392
    const size_t T1N  = 8 * 84 * 84;   // 56448
    const size_t T2N  = 8 * 76 * 76;   // 46208
    size_t per_img = (PADN + T1N + T2N) * sizeof(float);
    int CH = (int)(ws_size / per_img);
    if (CH > B_IMG) CH = B_IMG;
    if (CH < 1) CH = 1;
    float* pad = (float*)d_ws;
    float* t1  = pad + (size_t)CH * PADN;
    float* t2  = t1 + (size_t)CH * T1N;

    fc_kernel<<<dim3(57, 8), 256, 0, stream>>>(x, fcw, fcb, h);

    for (int it = 0; it < 5; ++it) {
        for (int c0 = 0; c0 < B_IMG; c0 += CH) {
            int cn = (B_IMG - c0) < CH ? (B_IMG - c0) : CH;
            pad_kernel<<<cn, 256, 0, stream>>>(x + (size_t)c0 * 3600,
                                               h + (size_t)c0 * 3600, pad);
            // conv1: NP=84*21=1764 -> 7 blocks; conv2: 76*19=1444 -> 6;
            // conv3: 68*17=1156 -> 5; conv4: 450 -> 2
            convA<3, 92, true><<<dim3(7, cn), 256, 0, stream>>>(pad, w1, b1, t1);
            convA<8, 84, true><<<dim3(6, cn), 256, 0, stream>>>(t1, w2, b2, t2);
            convA<8, 76, true><<<dim3(5, cn), 256, 0, stream>>>(t2, w3, b3, t1);
            convB<<<dim3(2, cn), 256, 0, stream>>>(t1, w4, b4,
                                                   h + (size_t)c0 * 3600);
        }
    }
}